// Round 3
// baseline (1609.770 us; speedup 1.0000x reference)
//
#include <hip/hip_runtime.h>
#include <hip/hip_fp16.h>
#include <math.h>

#define FIN 35
#define F1  64
#define BSZ 256          // nodes per dst bucket (fixed by facc = 256*64*4B = 64KB LDS)
#define BSH 8            // log2(BSZ)
#define NRG 8            // src ranges per dst bucket
#define RSH 14           // src range = 16384 nodes = 2MB of g1 (fits per-XCD 4MB L2)
#define PCH 8192         // edges per chunk in hist/place
#define KCAP 3584        // 512*7 >= NBK = ceil(n/256)*8 ; supports n <= 114688

// ---------- phase 1: per-chunk histogram of (dst-bucket, src-range) keys ----------
__global__ void k_hist(const int* __restrict__ src, const int* __restrict__ dst,
                       int* __restrict__ kcnt, int E, int NBK) {
    __shared__ int h[KCAP];
    int c = blockIdx.x, t = threadIdx.x;
    for (int i = t; i < KCAP; i += 256) h[i] = 0;
    __syncthreads();
    int e0 = c * PCH, e1 = min(e0 + PCH, E);
    bool al = ((((size_t)(dst + e0)) | ((size_t)(src + e0))) & 15) == 0;
    int nv = al ? ((e1 - e0) >> 2) : 0;
    const int4* d4 = (const int4*)(dst + e0);
    const int4* s4 = (const int4*)(src + e0);
    for (int i = t; i < nv; i += 256) {
        int4 d = d4[i]; int4 s = s4[i];
        atomicAdd(&h[((d.x >> BSH) << 3) | (s.x >> RSH)], 1);
        atomicAdd(&h[((d.y >> BSH) << 3) | (s.y >> RSH)], 1);
        atomicAdd(&h[((d.z >> BSH) << 3) | (s.z >> RSH)], 1);
        atomicAdd(&h[((d.w >> BSH) << 3) | (s.w >> RSH)], 1);
    }
    for (int e = e0 + (nv << 2) + t; e < e1; e += 256)
        atomicAdd(&h[((dst[e] >> BSH) << 3) | (src[e] >> RSH)], 1);
    __syncthreads();
    for (int k = t; k < NBK; k += 256) { int v = h[k]; if (v) atomicAdd(&kcnt[k], v); }
}

// ---------- phase 2: exclusive scan of key counts -> segment bases (NBK <= 4096) ----------
__global__ void k_scan_buck(const int* __restrict__ kcnt, int* __restrict__ boff,
                            int NBK, int E) {
    __shared__ int s[1024];
    int t = threadIdx.x;
    int base = t * 4;
    int a0 = (base     < NBK) ? kcnt[base]     : 0;
    int a1 = (base + 1 < NBK) ? kcnt[base + 1] : 0;
    int a2 = (base + 2 < NBK) ? kcnt[base + 2] : 0;
    int a3 = (base + 3 < NBK) ? kcnt[base + 3] : 0;
    int p1 = a0, p2 = p1 + a1, p3 = p2 + a2, tot = p3 + a3;
    s[t] = tot;
    __syncthreads();
    #pragma unroll
    for (int off = 1; off < 1024; off <<= 1) {
        int tv = (t >= off) ? s[t - off] : 0;
        __syncthreads();
        s[t] += tv;
        __syncthreads();
    }
    int tex = s[t] - tot;
    if (base     < NBK) boff[base]     = tex;
    if (base + 1 < NBK) boff[base + 1] = tex + p1;
    if (base + 2 < NBK) boff[base + 2] = tex + p2;
    if (base + 3 < NBK) boff[base + 3] = tex + p3;
    if (t == 0) boff[NBK] = E;
}

// ---------- phase 3: placement — LDS counting sort per chunk, atomic window claim,
// ---------- coalesced bucket-major output. rec = (src<<7 | dl<<24, ew) ----------
__global__ __launch_bounds__(512) void k_place(
        const int* __restrict__ src, const int* __restrict__ dst,
        const float* __restrict__ ew, const int* __restrict__ boff,
        int* __restrict__ gcur, int2* __restrict__ recs, int E, int NBK) {
    extern __shared__ char pmem[];
    int2* lrec   = (int2*)pmem;              // PCH records (64 KB)
    int*  addr32 = (int*)(lrec + PCH);       // PCH global addresses (32 KB)
    int*  s      = addr32 + PCH;             // KCAP counts -> exclusive prefix
    int*  cur    = s + KCAP;                 // KCAP chunk-local cursors
    int*  gwin   = cur + KCAP;               // KCAP global window bases
    __shared__ int ts[512];
    int c = blockIdx.x, t = threadIdx.x;
    for (int i = t; i < KCAP; i += 512) { s[i] = 0; cur[i] = 0; }
    __syncthreads();
    int e0 = c * PCH, e1 = min(e0 + PCH, E);
    bool al = ((((size_t)(dst + e0)) | ((size_t)(src + e0)) | ((size_t)(ew + e0))) & 15) == 0;
    int nv = al ? ((e1 - e0) >> 2) : 0;
    const int4*   s4 = (const int4*)(src + e0);
    const int4*   d4 = (const int4*)(dst + e0);
    const float4* w4 = (const float4*)(ew + e0);
    // pass A: count per key
    for (int i = t; i < nv; i += 512) {
        int4 d = d4[i]; int4 sv = s4[i];
        atomicAdd(&s[((d.x >> BSH) << 3) | (sv.x >> RSH)], 1);
        atomicAdd(&s[((d.y >> BSH) << 3) | (sv.y >> RSH)], 1);
        atomicAdd(&s[((d.z >> BSH) << 3) | (sv.z >> RSH)], 1);
        atomicAdd(&s[((d.w >> BSH) << 3) | (sv.w >> RSH)], 1);
    }
    for (int e = e0 + (nv << 2) + t; e < e1; e += 512)
        atomicAdd(&s[((dst[e] >> BSH) << 3) | (src[e] >> RSH)], 1);
    __syncthreads();
    // claim global windows (order within a segment is irrelevant: sums commute)
    for (int k = t; k < NBK; k += 512) {
        int lc = s[k];
        if (lc) gwin[k] = boff[k] + atomicAdd(&gcur[k], lc);
    }
    __syncthreads();
    // in-place exclusive scan of s over KCAP = 512*7 (7 elems/thread + HS over thread sums)
    int base = t * 7;
    int a0=s[base],a1=s[base+1],a2=s[base+2],a3=s[base+3],a4=s[base+4],a5=s[base+5],a6=s[base+6];
    int p1=a0,p2=p1+a1,p3=p2+a2,p4=p3+a3,p5=p4+a4,p6=p5+a5,tot=p6+a6;
    ts[t] = tot;
    __syncthreads();
    #pragma unroll
    for (int off = 1; off < 512; off <<= 1) {
        int tv = (t >= off) ? ts[t - off] : 0;
        __syncthreads();
        ts[t] += tv;
        __syncthreads();
    }
    int tex = ts[t] - tot;
    s[base]=tex; s[base+1]=tex+p1; s[base+2]=tex+p2; s[base+3]=tex+p3;
    s[base+4]=tex+p4; s[base+5]=tex+p5; s[base+6]=tex+p6;
    __syncthreads();
    // pass B: scatter into LDS (record + final global address)
    for (int i = t; i < nv; i += 512) {
        int4 sv = s4[i]; int4 d = d4[i]; float4 wv = w4[i];
        int k, r, sl;
        k=((d.x>>BSH)<<3)|(sv.x>>RSH); r=atomicAdd(&cur[k],1); sl=s[k]+r;
        lrec[sl]=make_int2((sv.x<<7)|((d.x&(BSZ-1))<<24), __float_as_int(wv.x)); addr32[sl]=gwin[k]+r;
        k=((d.y>>BSH)<<3)|(sv.y>>RSH); r=atomicAdd(&cur[k],1); sl=s[k]+r;
        lrec[sl]=make_int2((sv.y<<7)|((d.y&(BSZ-1))<<24), __float_as_int(wv.y)); addr32[sl]=gwin[k]+r;
        k=((d.z>>BSH)<<3)|(sv.z>>RSH); r=atomicAdd(&cur[k],1); sl=s[k]+r;
        lrec[sl]=make_int2((sv.z<<7)|((d.z&(BSZ-1))<<24), __float_as_int(wv.z)); addr32[sl]=gwin[k]+r;
        k=((d.w>>BSH)<<3)|(sv.w>>RSH); r=atomicAdd(&cur[k],1); sl=s[k]+r;
        lrec[sl]=make_int2((sv.w<<7)|((d.w&(BSZ-1))<<24), __float_as_int(wv.w)); addr32[sl]=gwin[k]+r;
    }
    for (int e = e0 + (nv << 2) + t; e < e1; e += 512) {
        int d = dst[e];
        int k = ((d >> BSH) << 3) | (src[e] >> RSH);
        int r = atomicAdd(&cur[k], 1); int sl = s[k] + r;
        lrec[sl] = make_int2((src[e] << 7) | ((d & (BSZ-1)) << 24), __float_as_int(ew[e]));
        addr32[sl] = gwin[k] + r;
    }
    __syncthreads();
    // pass C: linear LDS walk -> coalesced global stores
    int cnt = e1 - e0;
    for (int i = t; i < cnt; i += 512) recs[addr32[i]] = lrec[i];
}

// ---------- weighted in-degree -> dinv ----------
__global__ __launch_bounds__(256) void k_deg(
        const int* __restrict__ boff, const int2* __restrict__ recs,
        float* __restrict__ dinv, int n) {
    __shared__ float ds[BSZ];
    int t = threadIdx.x, b = blockIdx.x;
    ds[t] = 1.0f;                            // self-loop weight
    __syncthreads();
    int s0 = boff[b * NRG], s1 = boff[b * NRG + NRG];
    for (int i = s0 + t; i < s1; i += 256) {
        int2 rc = recs[i];
        atomicAdd(&ds[(unsigned)rc.x >> 24], __int_as_float(rc.y));
    }
    __syncthreads();
    int node = b * BSZ + t;
    if (node < n) dinv[node] = rsqrtf(ds[t]);
}

// ---------- layer 1 GEMM: g1 = fp16(dinv*x@W1), plain row-major ----------
__global__ void k_gemm1(const float* __restrict__ x, const float* __restrict__ W1,
                        const float* __restrict__ dinv, __half* __restrict__ g1, int n) {
    __shared__ float W1s[FIN * F1];
    __shared__ float xs[64 * FIN];
    int t = threadIdx.x;
    for (int i = t; i < (FIN * F1) / 4; i += 256) ((float4*)W1s)[i] = ((const float4*)W1)[i];
    int row0 = blockIdx.x * 64;
    int nrows = min(64, n - row0);
    const float* xbase = x + (size_t)row0 * FIN;
    int tot = nrows * FIN;
    int totv = tot >> 2;
    for (int i = t; i < totv; i += 256) ((float4*)xs)[i] = ((const float4*)xbase)[i];
    for (int i = (totv << 2) + t; i < tot; i += 256) xs[i] = xbase[i];
    __syncthreads();
    int wave = t >> 6, f = t & 63;
    for (int rl = wave; rl < nrows; rl += 4) {
        float acc = 0.0f;
        #pragma unroll
        for (int k = 0; k < FIN; k++) acc += xs[rl * FIN + k] * W1s[k * F1 + f];
        int row = row0 + rl;
        g1[(size_t)row * F1 + f] = __float2half(acc * dinv[row]);
    }
}

// ---------- fused layer-1 aggregate (LDS accumulate, src-range blocked)
// ---------- + self-loop + bias + ReLU + layer-2 GEMM (64->2) ----------
// v3: WAVE-UNIFORM record processing (round-0 proven structure): one record per
// wave, lane ln reads feature ln (2B) of the g1 row; record index forced uniform
// via readfirstlane so records scalarize into SGPRs; 8 records unrolled as named
// scalars (no per-lane arrays -> no scratch).
__global__ __launch_bounds__(1024) void k_agg1(
        const int* __restrict__ boff, const int2* __restrict__ recs,
        const __half* __restrict__ g1, const float* __restrict__ dinv,
        const float* __restrict__ b1, const float* __restrict__ W2,
        float* __restrict__ g2, int n) {
    extern __shared__ float facc[];          // BSZ*F1 fp32 = 64 KB
    int t = threadIdx.x, b = blockIdx.x;
    for (int i = t; i < (BSZ * F1) >> 2; i += 1024)
        ((float4*)facc)[i] = make_float4(0.f, 0.f, 0.f, 0.f);
    __syncthreads();
    int wv = t >> 6;                         // wave 0..15
    int ln = t & 63;                         // lane = feature
    const char* g1b = (const char*)g1 + ln * 2;
    #pragma unroll 1
    for (int rg = 0; rg < NRG; rg++) {       // ranges in order: g1 window L2-resident
        int s0 = boff[b * NRG + rg], s1 = boff[b * NRG + rg + 1];
        for (int base = s0 + wv * 8; base < s1; base += 128) {
            if (base + 8 <= s1) {
                int ub = __builtin_amdgcn_readfirstlane(base);
                int2 r0 = recs[ub],     r1 = recs[ub + 1], r2 = recs[ub + 2], r3 = recs[ub + 3];
                int2 r4 = recs[ub + 4], r5 = recs[ub + 5], r6 = recs[ub + 6], r7 = recs[ub + 7];
                float v0 = __half2float(*(const __half*)(g1b + ((unsigned)r0.x & 0xFFFFFF)));
                float v1 = __half2float(*(const __half*)(g1b + ((unsigned)r1.x & 0xFFFFFF)));
                float v2 = __half2float(*(const __half*)(g1b + ((unsigned)r2.x & 0xFFFFFF)));
                float v3 = __half2float(*(const __half*)(g1b + ((unsigned)r3.x & 0xFFFFFF)));
                float v4 = __half2float(*(const __half*)(g1b + ((unsigned)r4.x & 0xFFFFFF)));
                float v5 = __half2float(*(const __half*)(g1b + ((unsigned)r5.x & 0xFFFFFF)));
                float v6 = __half2float(*(const __half*)(g1b + ((unsigned)r6.x & 0xFFFFFF)));
                float v7 = __half2float(*(const __half*)(g1b + ((unsigned)r7.x & 0xFFFFFF)));
                atomicAdd(&facc[((((unsigned)r0.x) >> 24) << 6) + ln], __int_as_float(r0.y) * v0);
                atomicAdd(&facc[((((unsigned)r1.x) >> 24) << 6) + ln], __int_as_float(r1.y) * v1);
                atomicAdd(&facc[((((unsigned)r2.x) >> 24) << 6) + ln], __int_as_float(r2.y) * v2);
                atomicAdd(&facc[((((unsigned)r3.x) >> 24) << 6) + ln], __int_as_float(r3.y) * v3);
                atomicAdd(&facc[((((unsigned)r4.x) >> 24) << 6) + ln], __int_as_float(r4.y) * v4);
                atomicAdd(&facc[((((unsigned)r5.x) >> 24) << 6) + ln], __int_as_float(r5.y) * v5);
                atomicAdd(&facc[((((unsigned)r6.x) >> 24) << 6) + ln], __int_as_float(r6.y) * v6);
                atomicAdd(&facc[((((unsigned)r7.x) >> 24) << 6) + ln], __int_as_float(r7.y) * v7);
            } else {
                for (int idx = base; idx < s1; idx++) {
                    int2 rc = recs[idx];
                    float v = __half2float(*(const __half*)(g1b + ((unsigned)rc.x & 0xFFFFFF)));
                    atomicAdd(&facc[((((unsigned)rc.x) >> 24) << 6) + ln],
                              __int_as_float(rc.y) * v);
                }
            }
        }
    }
    __syncthreads();
    // epilogue: 16 waves x 16 nodes each
    int f = ln;
    float bf = b1[f];
    float2 w2v = ((const float2*)W2)[f];
    for (int dl = wv; dl < BSZ; dl += 16) {
        int node = b * BSZ + dl;
        if (node >= n) break;
        float dv = dinv[node];
        float selfv = __half2float(g1[(size_t)node * F1 + f]);
        float h = dv * (facc[(dl << 6) + f] + selfv) + bf;   // self-loop w=1
        h = h > 0.0f ? h : 0.0f;
        float z0 = h * w2v.x, z1 = h * w2v.y;
        #pragma unroll
        for (int off = 32; off > 0; off >>= 1) {
            z0 += __shfl_xor(z0, off, 64);
            z1 += __shfl_xor(z1, off, 64);
        }
        if (f == 0) {
            g2[(size_t)node * 2 + 0] = dv * z0;
            g2[(size_t)node * 2 + 1] = dv * z1;
        }
    }
}

// ---------- fused layer-2 aggregate (LDS accumulate) + bias + log_softmax ----------
__global__ __launch_bounds__(256) void k_agg2(
        const int* __restrict__ boff, const int2* __restrict__ recs,
        const float* __restrict__ g2, const float* __restrict__ dinv,
        const float* __restrict__ b2, float* __restrict__ out, int n) {
    __shared__ float a2[BSZ * 2];
    int t = threadIdx.x, b = blockIdx.x;
    a2[t] = 0.0f; a2[t + 256] = 0.0f;
    __syncthreads();
    int s0 = boff[b * NRG], s1 = boff[b * NRG + NRG];
    const char* g2b = (const char*)g2;
    int i = s0 + t;
    for (; i + 768 < s1; i += 1024) {        // 4 gathers in flight
        int2 r0 = recs[i], r1 = recs[i + 256], r2 = recs[i + 512], r3 = recs[i + 768];
        float2 v0 = *(const float2*)(g2b + (((unsigned)r0.x & 0xFFFFFF) >> 4));
        float2 v1 = *(const float2*)(g2b + (((unsigned)r1.x & 0xFFFFFF) >> 4));
        float2 v2 = *(const float2*)(g2b + (((unsigned)r2.x & 0xFFFFFF) >> 4));
        float2 v3 = *(const float2*)(g2b + (((unsigned)r3.x & 0xFFFFFF) >> 4));
        int d0 = (unsigned)r0.x >> 24, d1 = (unsigned)r1.x >> 24;
        int d2 = (unsigned)r2.x >> 24, d3 = (unsigned)r3.x >> 24;
        float w0 = __int_as_float(r0.y), w1 = __int_as_float(r1.y);
        float w2 = __int_as_float(r2.y), w3 = __int_as_float(r3.y);
        atomicAdd(&a2[d0*2], w0*v0.x); atomicAdd(&a2[d0*2+1], w0*v0.y);
        atomicAdd(&a2[d1*2], w1*v1.x); atomicAdd(&a2[d1*2+1], w1*v1.y);
        atomicAdd(&a2[d2*2], w2*v2.x); atomicAdd(&a2[d2*2+1], w2*v2.y);
        atomicAdd(&a2[d3*2], w3*v3.x); atomicAdd(&a2[d3*2+1], w3*v3.y);
    }
    for (; i < s1; i += 256) {
        int2 rc = recs[i];
        float2 gv = *(const float2*)(g2b + (((unsigned)rc.x & 0xFFFFFF) >> 4));
        float w = __int_as_float(rc.y);
        int dl = (unsigned)rc.x >> 24;
        atomicAdd(&a2[dl*2], w*gv.x); atomicAdd(&a2[dl*2+1], w*gv.y);
    }
    __syncthreads();
    int node = b * BSZ + t;
    if (node < n) {
        float dv = dinv[node];
        float2 sv = ((const float2*)g2)[node];     // self-loop
        float z0 = dv * (a2[t*2]     + sv.x) + b2[0];
        float z1 = dv * (a2[t*2 + 1] + sv.y) + b2[1];
        float m = fmaxf(z0, z1);
        float lse = m + logf(expf(z0 - m) + expf(z1 - m));
        ((float2*)out)[node] = make_float2(z0 - lse, z1 - lse);
    }
}

extern "C" void kernel_launch(void* const* d_in, const int* in_sizes, int n_in,
                              void* d_out, int out_size, void* d_ws, size_t ws_size,
                              hipStream_t stream) {
    const float* x  = (const float*)d_in[0];
    const int*   ei = (const int*)d_in[1];    // [2, E]: src row then dst row
    const float* ew = (const float*)d_in[2];
    const float* W1 = (const float*)d_in[3];
    const float* b1 = (const float*)d_in[4];
    const float* W2 = (const float*)d_in[5];
    const float* b2 = (const float*)d_in[6];
    float* out = (float*)d_out;

    int n = in_sizes[0] / FIN;
    int E = in_sizes[2];
    const int* src = ei;
    const int* dst = ei + E;
    int NB  = (n + BSZ - 1) / BSZ;            // 391 for n=100000
    int NBK = NB * NRG;                       // 3128 <= KCAP
    int NCHUNK = (E + PCH - 1) / PCH;         // 391 for E=3.2M

    // workspace carve-out, 16B-aligned
    char* ws = (char*)d_ws;
    size_t off = 0;
    auto alloc = [&](size_t bytes) -> void* {
        void* p = ws + off;
        off += (bytes + 15) & ~(size_t)15;
        return p;
    };
    int*    cnts = (int*)   alloc((size_t)2 * NBK * 4);  // kcnt | gcur
    int*    kcnt = cnts;
    int*    gcur = cnts + NBK;
    int*    boff = (int*)   alloc((size_t)(NBK + 1) * 4);
    float*  dinv = (float*) alloc((size_t)n * 4);
    int2*   recs = (int2*)  alloc((size_t)E * 8);        // 25.6 MB (key-grouped)
    __half* g1   = (__half*)alloc((size_t)n * F1 * 2);   // 12.8 MB
    float*  g2   = (float*) alloc((size_t)n * 2 * 4);

    size_t place_lds = (size_t)PCH * 8 + (size_t)PCH * 4 + 3 * (size_t)KCAP * 4; // 141.3 KB
    size_t agg1_lds  = (size_t)BSZ * F1 * 4;                                     // 64 KB

    hipMemsetAsync(cnts, 0, (size_t)2 * NBK * 4, stream);
    k_hist     <<<NCHUNK, 256, 0, stream>>>(src, dst, kcnt, E, NBK);
    k_scan_buck<<<1, 1024, 0, stream>>>(kcnt, boff, NBK, E);
    k_place    <<<NCHUNK, 512, place_lds, stream>>>(src, dst, ew, boff, gcur, recs, E, NBK);
    k_deg      <<<NB, 256, 0, stream>>>(boff, recs, dinv, n);
    k_gemm1    <<<(n + 63) / 64, 256, 0, stream>>>(x, W1, dinv, g1, n);
    k_agg1     <<<NB, 1024, agg1_lds, stream>>>(boff, recs, g1, dinv, b1, W2, g2, n);
    k_agg2     <<<NB, 256, 0, stream>>>(boff, recs, g2, dinv, b2, out, n);
}

// Round 4
// 298.305 us; speedup vs baseline: 5.3964x; 5.3964x over previous
//
#include <hip/hip_runtime.h>
#include <hip/hip_fp16.h>
#include <math.h>

#define FIN 35
#define F1  64
#define BSZ 256          // nodes per coarse bucket
#define BSH 8            // log2(BSZ)
#define GSH 7            // log2(g1 row bytes) = log2(64 feats * 2B)
#define MAXNB 512        // max buckets (n <= 131072)
#define PCH 8192         // edges per hist/place chunk => NCHUNK <= 512 for E <= 4.19M
#define SCAP 12288       // max bucket size for k_sort inv16 path (avg bucket ~8.2K)

// ---------- phase 1: per-chunk histogram of coarse buckets ----------
__global__ void k_hist(const int* __restrict__ dst, int* __restrict__ cmat,
                       int E, int NB, int NCHUNK) {
    __shared__ int h[MAXNB];
    int c = blockIdx.x, t = threadIdx.x;
    for (int i = t; i < NB; i += 256) h[i] = 0;
    __syncthreads();
    int e0 = c * PCH, e1 = min(e0 + PCH, E);
    bool al = ((size_t)(dst + e0) & 15) == 0;
    int nv = al ? ((e1 - e0) >> 2) : 0;
    const int4* d4 = (const int4*)(dst + e0);
    for (int i = t; i < nv; i += 256) {
        int4 v = d4[i];
        atomicAdd(&h[v.x >> BSH], 1); atomicAdd(&h[v.y >> BSH], 1);
        atomicAdd(&h[v.z >> BSH], 1); atomicAdd(&h[v.w >> BSH], 1);
    }
    for (int e = e0 + (nv << 2) + t; e < e1; e += 256) atomicAdd(&h[dst[e] >> BSH], 1);
    __syncthreads();
    for (int i = t; i < NB; i += 256) cmat[(size_t)i * NCHUNK + c] = h[i];  // b-major
}

// ---------- phase 2a: row-local exclusive scan (one block per bucket row; NCHUNK <= 512) ----------
__global__ void k_scan_row(int* __restrict__ cmat, int* __restrict__ rsum, int NCHUNK) {
    __shared__ int s[512];
    int b = blockIdx.x, t = threadIdx.x;
    int v = (t < NCHUNK) ? cmat[(size_t)b * NCHUNK + t] : 0;
    s[t] = v;
    __syncthreads();
    #pragma unroll
    for (int off = 1; off < 512; off <<= 1) {
        int tv = (t >= off) ? s[t - off] : 0;
        __syncthreads();
        s[t] += tv;
        __syncthreads();
    }
    if (t < NCHUNK) cmat[(size_t)b * NCHUNK + t] = s[t] - v;   // row-local exclusive
    if (t == 511) rsum[b] = s[511];                            // row total
}

// ---------- phase 2b: exclusive scan of row totals -> bucket bases + boff (NB <= 1024) ----------
__global__ void k_scan_buck(const int* __restrict__ rsum, int* __restrict__ bbase,
                            int* __restrict__ boff, int NB, int E) {
    __shared__ int s[1024];
    int t = threadIdx.x;
    int v = (t < NB) ? rsum[t] : 0;
    s[t] = v;
    __syncthreads();
    #pragma unroll
    for (int off = 1; off < 1024; off <<= 1) {
        int tv = (t >= off) ? s[t - off] : 0;
        __syncthreads();
        s[t] += tv;
        __syncthreads();
    }
    if (t < NB) {
        int excl = s[t] - v;
        bbase[t] = excl;
        boff[t] = excl;
    }
    if (t == 0) boff[NB] = E;
}

// ---------- phase 3: placement — chunk-local LDS counting sort -> coalesced output ----------
__global__ __launch_bounds__(512) void k_place(
        const int* __restrict__ src, const int* __restrict__ dst,
        const float* __restrict__ ew, const int* __restrict__ cmat,
        const int* __restrict__ bbase,
        int2* __restrict__ recs, int E, int NB, int NCHUNK) {
    extern __shared__ char pmem[];
    int2* lrec   = (int2*)pmem;              // PCH records (64 KB)
    int*  addr32 = (int*)(lrec + PCH);       // PCH global addresses (32 KB)
    __shared__ int s[512];                   // counts -> inclusive scan
    __shared__ int lbase[512];               // chunk-local bucket base
    __shared__ int cur[512];                 // chunk-local cursor
    __shared__ int gwin[512];                // global window base per bucket
    int c = blockIdx.x, t = threadIdx.x;
    s[t] = 0;
    __syncthreads();
    int e0 = c * PCH, e1 = min(e0 + PCH, E);
    bool al = (((size_t)(dst + e0) | (size_t)(src + e0) | (size_t)(ew + e0)) & 15) == 0;
    int nv = al ? ((e1 - e0) >> 2) : 0;
    const int4*   s4 = (const int4*)(src + e0);
    const int4*   d4 = (const int4*)(dst + e0);
    const float4* w4 = (const float4*)(ew + e0);
    // pass A: count
    for (int i = t; i < nv; i += 512) {
        int4 v = d4[i];
        atomicAdd(&s[v.x >> BSH], 1); atomicAdd(&s[v.y >> BSH], 1);
        atomicAdd(&s[v.z >> BSH], 1); atomicAdd(&s[v.w >> BSH], 1);
    }
    for (int e = e0 + (nv << 2) + t; e < e1; e += 512) atomicAdd(&s[dst[e] >> BSH], 1);
    __syncthreads();
    int v = s[t];
    __syncthreads();
    #pragma unroll
    for (int off = 1; off < 512; off <<= 1) {
        int tv = (t >= off) ? s[t - off] : 0;
        __syncthreads();
        s[t] += tv;
        __syncthreads();
    }
    lbase[t] = s[t] - v;
    cur[t] = 0;
    gwin[t] = (t < NB) ? (cmat[(size_t)t * NCHUNK + c] + bbase[t]) : 0;
    __syncthreads();
    // pass B: scatter into LDS (record + final global address)
    for (int i = t; i < nv; i += 512) {
        int4   sv = s4[i];
        int4   dv = d4[i];
        float4 wv = w4[i];
        int b, r, sl;
        b = dv.x >> BSH; r = atomicAdd(&cur[b], 1); sl = lbase[b] + r;
        lrec[sl] = make_int2(sv.x | ((dv.x & (BSZ-1)) << 24), __float_as_int(wv.x));
        addr32[sl] = gwin[b] + r;
        b = dv.y >> BSH; r = atomicAdd(&cur[b], 1); sl = lbase[b] + r;
        lrec[sl] = make_int2(sv.y | ((dv.y & (BSZ-1)) << 24), __float_as_int(wv.y));
        addr32[sl] = gwin[b] + r;
        b = dv.z >> BSH; r = atomicAdd(&cur[b], 1); sl = lbase[b] + r;
        lrec[sl] = make_int2(sv.z | ((dv.z & (BSZ-1)) << 24), __float_as_int(wv.z));
        addr32[sl] = gwin[b] + r;
        b = dv.w >> BSH; r = atomicAdd(&cur[b], 1); sl = lbase[b] + r;
        lrec[sl] = make_int2(sv.w | ((dv.w & (BSZ-1)) << 24), __float_as_int(wv.w));
        addr32[sl] = gwin[b] + r;
    }
    for (int e = e0 + (nv << 2) + t; e < e1; e += 512) {
        int d = dst[e];
        int b = d >> BSH;
        int r = atomicAdd(&cur[b], 1);
        int sl = lbase[b] + r;
        lrec[sl] = make_int2(src[e] | ((d & (BSZ-1)) << 24), __float_as_int(ew[e]));
        addr32[sl] = gwin[b] + r;
    }
    __syncthreads();
    // pass C: linear LDS walk -> coalesced bucket-major global stores
    int cnt = e1 - e0;
    for (int i = t; i < cnt; i += 512) recs[addr32[i]] = lrec[i];
}

// ---------- per-bucket counting sort via inverse permutation ----------
// 512 threads (8 waves) + 24KB LDS -> 4 blocks/CU: all 391 blocks co-resident
// in one occupancy round (no straggler tail). Records out carry src<<7.
__global__ __launch_bounds__(512) void k_sort(
        const int* __restrict__ boff, const int2* __restrict__ recs_in,
        int2* __restrict__ recs_out, int* __restrict__ row_ptr,
        float* __restrict__ dinv, int n) {
    extern __shared__ unsigned short inv16[];   // SCAP entries (24 KB)
    __shared__ int   hcnt[BSZ];
    __shared__ int   hoff[BSZ];
    __shared__ float dsum[BSZ];
    int b = blockIdx.x, t = threadIdx.x;
    if (t < BSZ) { hcnt[t] = 0; dsum[t] = 1.0f; }   // self-loop weight
    __syncthreads();
    int s0 = boff[b], s1 = boff[b + 1];
    int cnt = s1 - s0;
    // pass 1: histogram + weighted degree (coalesced global read)
    for (int i = t; i < cnt; i += 512) {
        int2 rc = recs_in[s0 + i];
        int dl = ((unsigned)rc.x) >> 24;
        atomicAdd(&hcnt[dl], 1);
        atomicAdd(&dsum[dl], __int_as_float(rc.y));
    }
    __syncthreads();
    int v = 0;
    if (t < BSZ) { v = hcnt[t]; hoff[t] = v; }
    __syncthreads();
    #pragma unroll
    for (int off = 1; off < BSZ; off <<= 1) {
        int tv = 0;
        if (t < BSZ && t >= off) tv = hoff[t - off];
        __syncthreads();
        if (t < BSZ) hoff[t] += tv;
        __syncthreads();
    }
    if (t < BSZ) {
        int excl = hoff[t] - v;
        int node = b * BSZ + t;
        if (node < n) {
            row_ptr[node] = s0 + excl;
            dinv[node] = rsqrtf(dsum[t]);
            if (node == n - 1) row_ptr[n] = s1;
        }
        hcnt[t] = excl;           // reuse as local cursor
    }
    __syncthreads();
    if (cnt <= SCAP) {
        // pass 2: positions -> inverse index (cnt <= SCAP < 65536 fits u16)
        for (int i = t; i < cnt; i += 512) {
            int2 rc = recs_in[s0 + i];
            int dl = ((unsigned)rc.x) >> 24;
            int pos = atomicAdd(&hcnt[dl], 1);
            inv16[pos] = (unsigned short)i;
        }
        __syncthreads();
        // pass 3: linear positions -> coalesced stores
        for (int o = t; o < cnt; o += 512) {
            int2 rc = recs_in[s0 + inv16[o]];
            recs_out[s0 + o] = make_int2((rc.x & 0xFFFFFF) << GSH, rc.y);
        }
    } else {
        // fallback (bucket larger than SCAP — not expected): direct scatter
        for (int i = t; i < cnt; i += 512) {
            int2 rc = recs_in[s0 + i];
            int dl = ((unsigned)rc.x) >> 24;
            int pos = atomicAdd(&hcnt[dl], 1);
            recs_out[s0 + pos] = make_int2((rc.x & 0xFFFFFF) << GSH, rc.y);
        }
    }
}

// ---------- layer 1 GEMM: 64 rows/block; float4-staged; g1 = fp16(dinv*x@W1) ----------
__global__ void k_gemm1(const float* __restrict__ x, const float* __restrict__ W1,
                        const float* __restrict__ dinv, __half* __restrict__ g1, int n) {
    __shared__ float W1s[FIN * F1];    // 8960 B
    __shared__ float xs[64 * FIN];     // 8960 B
    int t = threadIdx.x;
    // W1: 2240 floats, 16B-aligned -> 560 float4
    for (int i = t; i < (FIN * F1) / 4; i += 256) ((float4*)W1s)[i] = ((const float4*)W1)[i];
    int row0 = blockIdx.x * 64;
    int nrows = min(64, n - row0);
    // x slice starts at byte offset blockIdx*64*35*4 = blockIdx*8960 (16B-aligned)
    const float* xbase = x + (size_t)row0 * FIN;
    int tot = nrows * FIN;
    int totv = tot >> 2;
    for (int i = t; i < totv; i += 256) ((float4*)xs)[i] = ((const float4*)xbase)[i];
    for (int i = (totv << 2) + t; i < tot; i += 256) xs[i] = xbase[i];
    __syncthreads();
    int wave = t >> 6, f = t & 63;
    for (int rl = wave; rl < nrows; rl += 4) {
        float acc = 0.0f;
        #pragma unroll
        for (int k = 0; k < FIN; k++) acc += xs[rl * FIN + k] * W1s[k * F1 + f];
        int row = row0 + rl;
        g1[(size_t)row * F1 + f] = __float2half(acc * dinv[row]);
    }
}

// ---------- fused: layer-1 gather (fp16 rows, 16-way MLP, prescaled offsets)
// ---------- + ReLU + layer-2 GEMM (64->2) ----------
__global__ void k_gather1(const int* __restrict__ rp, const int2* __restrict__ csr,
                          const __half* __restrict__ g1,
                          const float* __restrict__ dinv, const float* __restrict__ b1,
                          const float* __restrict__ W2, float* __restrict__ g2, int n) {
    int wid = (int)((blockIdx.x * (long long)blockDim.x + threadIdx.x) >> 6);
    int f = threadIdx.x & 63;
    if (wid >= n) return;
    const char* g1b = (const char*)g1 + f * 2;   // lane's feature column
    int start = rp[wid], end = rp[wid + 1];
    float acc = 0.0f;
    int e = start;
    for (; e + 16 <= end; e += 16) {           // 16 row-gathers in flight
        float a[16];
        int2 r[16];
        #pragma unroll
        for (int j = 0; j < 16; j++) r[j] = csr[e + j];
        #pragma unroll
        for (int j = 0; j < 16; j++)
            a[j] = __half2float(*(const __half*)(g1b + (unsigned)r[j].x));
        #pragma unroll
        for (int j = 0; j < 16; j++) acc += __int_as_float(r[j].y) * a[j];
    }
    for (; e + 4 <= end; e += 4) {
        int2 r0 = csr[e], r1 = csr[e+1], r2 = csr[e+2], r3 = csr[e+3];
        float a0 = __half2float(*(const __half*)(g1b + (unsigned)r0.x));
        float a1 = __half2float(*(const __half*)(g1b + (unsigned)r1.x));
        float a2 = __half2float(*(const __half*)(g1b + (unsigned)r2.x));
        float a3 = __half2float(*(const __half*)(g1b + (unsigned)r3.x));
        acc += __int_as_float(r0.y) * a0; acc += __int_as_float(r1.y) * a1;
        acc += __int_as_float(r2.y) * a2; acc += __int_as_float(r3.y) * a3;
    }
    for (; e < end; e++) {
        int2 r = csr[e];
        acc += __int_as_float(r.y) * __half2float(*(const __half*)(g1b + (unsigned)r.x));
    }
    float dv = dinv[wid];
    float h = dv * (acc + __half2float(g1[(size_t)wid * F1 + f])) + b1[f]; // self-loop w=1
    h = h > 0.0f ? h : 0.0f;
    float2 w2v = ((const float2*)W2)[f];
    float z0 = h * w2v.x, z1 = h * w2v.y;
    #pragma unroll
    for (int off = 32; off > 0; off >>= 1) {
        z0 += __shfl_xor(z0, off, 64);
        z1 += __shfl_xor(z1, off, 64);
    }
    if (f == 0) {
        g2[(size_t)wid * 2 + 0] = dv * z0;
        g2[(size_t)wid * 2 + 1] = dv * z1;
    }
}

// ---------- fused: layer-2 gather (2 nodes/wave, 32 lanes each) + bias + log_softmax ----------
__global__ void k_gather2(const int* __restrict__ rp, const int2* __restrict__ csr,
                          const float* __restrict__ g2,
                          const float* __restrict__ dinv, const float* __restrict__ b2,
                          float* __restrict__ out, int n) {
    int w = (int)((blockIdx.x * (long long)blockDim.x + threadIdx.x) >> 6);
    int lane = threadIdx.x & 63;
    int half = lane >> 5, sub = lane & 31;
    int node = w * 2 + half;
    if (node >= n) return;                      // uniform within each 32-lane half
    const char* g2b = (const char*)g2;
    int start = rp[node], end = rp[node + 1];
    float a0 = 0.0f, a1 = 0.0f;
    int e = start + sub;
    for (; e + 96 < end; e += 128) {            // 4 gathers in flight, stride 32
        int2 q0 = csr[e], q1 = csr[e + 32], q2 = csr[e + 64], q3 = csr[e + 96];
        float2 v0 = *(const float2*)(g2b + (((unsigned)q0.x) >> 4));
        float2 v1 = *(const float2*)(g2b + (((unsigned)q1.x) >> 4));
        float2 v2 = *(const float2*)(g2b + (((unsigned)q2.x) >> 4));
        float2 v3 = *(const float2*)(g2b + (((unsigned)q3.x) >> 4));
        a0 += __int_as_float(q0.y) * v0.x; a1 += __int_as_float(q0.y) * v0.y;
        a0 += __int_as_float(q1.y) * v1.x; a1 += __int_as_float(q1.y) * v1.y;
        a0 += __int_as_float(q2.y) * v2.x; a1 += __int_as_float(q2.y) * v2.y;
        a0 += __int_as_float(q3.y) * v3.x; a1 += __int_as_float(q3.y) * v3.y;
    }
    for (; e < end; e += 32) {
        int2 r = csr[e];
        float wt = __int_as_float(r.y);
        float2 gv = *(const float2*)(g2b + (((unsigned)r.x) >> 4));
        a0 += wt * gv.x; a1 += wt * gv.y;
    }
    #pragma unroll
    for (int off = 16; off > 0; off >>= 1) {    // reduce within the 32-lane half
        a0 += __shfl_xor(a0, off, 64);
        a1 += __shfl_xor(a1, off, 64);
    }
    if (sub == 0) {
        float dv = dinv[node];
        float2 sv = ((const float2*)g2)[node];       // self-loop
        float z0 = dv * (a0 + sv.x) + b2[0];
        float z1 = dv * (a1 + sv.y) + b2[1];
        float m = fmaxf(z0, z1);
        float lse = m + logf(expf(z0 - m) + expf(z1 - m));
        ((float2*)out)[node] = make_float2(z0 - lse, z1 - lse);
    }
}

extern "C" void kernel_launch(void* const* d_in, const int* in_sizes, int n_in,
                              void* d_out, int out_size, void* d_ws, size_t ws_size,
                              hipStream_t stream) {
    const float* x  = (const float*)d_in[0];
    const int*   ei = (const int*)d_in[1];    // [2, E]: src row then dst row
    const float* ew = (const float*)d_in[2];
    const float* W1 = (const float*)d_in[3];
    const float* b1 = (const float*)d_in[4];
    const float* W2 = (const float*)d_in[5];
    const float* b2 = (const float*)d_in[6];
    float* out = (float*)d_out;

    int n = in_sizes[0] / FIN;
    int E = in_sizes[2];
    const int* src = ei;
    const int* dst = ei + E;
    int NB = (n + BSZ - 1) / BSZ;             // 391 for n=100000 (<= MAXNB)
    int NCHUNK = (E + PCH - 1) / PCH;         // 391 for E=3.2M (<= 512 for k_scan_row)
    int M = NB * NCHUNK;

    // workspace carve-out, 16B-aligned
    char* ws = (char*)d_ws;
    size_t off = 0;
    auto alloc = [&](size_t bytes) -> void* {
        void* p = ws + off;
        off += (bytes + 15) & ~(size_t)15;
        return p;
    };
    int*    cmat    = (int*)   alloc((size_t)M * 4);      // 612 KB placement matrix
    int*    rsum    = (int*)   alloc((size_t)NB * 4);
    int*    bbase   = (int*)   alloc((size_t)NB * 4);
    int*    boff    = (int*)   alloc((size_t)(NB + 1) * 4);
    int*    row_ptr = (int*)   alloc((size_t)(n + 1) * 4);
    float*  dinv    = (float*) alloc((size_t)n * 4);
    int2*   recs_a  = (int2*)  alloc((size_t)E * 8);      // 25.6 MB (bucket order)
    int2*   recs_b  = (int2*)  alloc((size_t)E * 8);      // 25.6 MB (node order)
    __half* g1      = (__half*)alloc((size_t)n * F1 * 2); // 12.8 MB
    float*  g2      = (float*) alloc((size_t)n * 2 * 4);

    size_t place_lds = (size_t)PCH * 8 + (size_t)PCH * 4;    // lrec + addr32 = 96 KB
    size_t sort_lds  = (size_t)SCAP * 2;                     // inv16 = 24 KB

    int g2_waves = (n + 1) / 2 + 1;           // 2 nodes per wave

    k_hist     <<<NCHUNK, 256, 0, stream>>>(dst, cmat, E, NB, NCHUNK);
    k_scan_row <<<NB, 512, 0, stream>>>(cmat, rsum, NCHUNK);
    k_scan_buck<<<1, 1024, 0, stream>>>(rsum, bbase, boff, NB, E);
    k_place    <<<NCHUNK, 512, place_lds, stream>>>(src, dst, ew, cmat, bbase, recs_a, E, NB, NCHUNK);
    k_sort     <<<NB, 512, sort_lds, stream>>>(boff, recs_a, recs_b, row_ptr, dinv, n);
    k_gemm1    <<<(n + 63) / 64, 256, 0, stream>>>(x, W1, dinv, g1, n);
    k_gather1  <<<(n + 3) / 4, 256, 0, stream>>>(row_ptr, recs_b, g1, dinv, b1, W2, g2, n);
    k_gather2  <<<(g2_waves + 3) / 4, 256, 0, stream>>>(row_ptr, recs_b, g2, dinv, b2, out, n);
}

// Round 6
// 293.290 us; speedup vs baseline: 5.4887x; 1.0171x over previous
//
#include <hip/hip_runtime.h>
#include <hip/hip_fp16.h>
#include <math.h>

#define FIN 35
#define F1  64
#define BSZ 256          // nodes per coarse bucket
#define BSH 8            // log2(BSZ)
#define GSH 7            // log2(g1 row bytes) = log2(64 feats * 2B)
#define MAXNB 512        // max buckets (n <= 131072)
#define PCH 8192         // edges per hist/place chunk => NCHUNK <= 512 for E <= 4.19M
#define SCAP 12288       // max bucket size for k_sort inv16 path (avg bucket ~8.2K)

// ---------- phase 1: per-chunk histogram of coarse buckets ----------
__global__ void k_hist(const int* __restrict__ dst, int* __restrict__ cmat,
                       int E, int NB, int NCHUNK) {
    __shared__ int h[MAXNB];
    int c = blockIdx.x, t = threadIdx.x;
    for (int i = t; i < NB; i += 256) h[i] = 0;
    __syncthreads();
    int e0 = c * PCH, e1 = min(e0 + PCH, E);
    bool al = ((size_t)(dst + e0) & 15) == 0;
    int nv = al ? ((e1 - e0) >> 2) : 0;
    const int4* d4 = (const int4*)(dst + e0);
    for (int i = t; i < nv; i += 256) {
        int4 v = d4[i];
        atomicAdd(&h[v.x >> BSH], 1); atomicAdd(&h[v.y >> BSH], 1);
        atomicAdd(&h[v.z >> BSH], 1); atomicAdd(&h[v.w >> BSH], 1);
    }
    for (int e = e0 + (nv << 2) + t; e < e1; e += 256) atomicAdd(&h[dst[e] >> BSH], 1);
    __syncthreads();
    for (int i = t; i < NB; i += 256) cmat[(size_t)i * NCHUNK + c] = h[i];  // b-major
}

// ---------- phase 2a: row-local exclusive scan (one block per bucket row; NCHUNK <= 512) ----------
__global__ void k_scan_row(int* __restrict__ cmat, int* __restrict__ rsum, int NCHUNK) {
    __shared__ int s[512];
    int b = blockIdx.x, t = threadIdx.x;
    int v = (t < NCHUNK) ? cmat[(size_t)b * NCHUNK + t] : 0;
    s[t] = v;
    __syncthreads();
    #pragma unroll
    for (int off = 1; off < 512; off <<= 1) {
        int tv = (t >= off) ? s[t - off] : 0;
        __syncthreads();
        s[t] += tv;
        __syncthreads();
    }
    if (t < NCHUNK) cmat[(size_t)b * NCHUNK + t] = s[t] - v;   // row-local exclusive
    if (t == 511) rsum[b] = s[511];                            // row total
}

// ---------- phase 2b: exclusive scan of row totals -> bucket bases + boff (NB <= 1024) ----------
__global__ void k_scan_buck(const int* __restrict__ rsum, int* __restrict__ bbase,
                            int* __restrict__ boff, int NB, int E) {
    __shared__ int s[1024];
    int t = threadIdx.x;
    int v = (t < NB) ? rsum[t] : 0;
    s[t] = v;
    __syncthreads();
    #pragma unroll
    for (int off = 1; off < 1024; off <<= 1) {
        int tv = (t >= off) ? s[t - off] : 0;
        __syncthreads();
        s[t] += tv;
        __syncthreads();
    }
    if (t < NB) {
        int excl = s[t] - v;
        bbase[t] = excl;
        boff[t] = excl;
    }
    if (t == 0) boff[NB] = E;
}

// ---------- phase 3: placement — chunk-local LDS counting sort -> coalesced output ----------
// v2: no addr32 — pass C reconstructs gwin[b]+i via per-bucket copy. LDS 96->64 KB
// extern (+8 KB statics) => 2 blocks/CU, 391 blocks all co-resident (no tail round).
__global__ __launch_bounds__(512) void k_place(
        const int* __restrict__ src, const int* __restrict__ dst,
        const float* __restrict__ ew, const int* __restrict__ cmat,
        const int* __restrict__ bbase,
        int2* __restrict__ recs, int E, int NB, int NCHUNK) {
    extern __shared__ char pmem[];
    int2* lrec = (int2*)pmem;                // PCH records (64 KB)
    __shared__ int s[512];                   // counts -> inclusive scan
    __shared__ int lbase[512];               // chunk-local bucket base
    __shared__ int cur[512];                 // chunk-local cursor
    __shared__ int gwin[512];                // global window base per bucket
    int c = blockIdx.x, t = threadIdx.x;
    s[t] = 0;
    __syncthreads();
    int e0 = c * PCH, e1 = min(e0 + PCH, E);
    bool al = (((size_t)(dst + e0) | (size_t)(src + e0) | (size_t)(ew + e0)) & 15) == 0;
    int nv = al ? ((e1 - e0) >> 2) : 0;
    const int4*   s4 = (const int4*)(src + e0);
    const int4*   d4 = (const int4*)(dst + e0);
    const float4* w4 = (const float4*)(ew + e0);
    // pass A: count
    for (int i = t; i < nv; i += 512) {
        int4 v = d4[i];
        atomicAdd(&s[v.x >> BSH], 1); atomicAdd(&s[v.y >> BSH], 1);
        atomicAdd(&s[v.z >> BSH], 1); atomicAdd(&s[v.w >> BSH], 1);
    }
    for (int e = e0 + (nv << 2) + t; e < e1; e += 512) atomicAdd(&s[dst[e] >> BSH], 1);
    __syncthreads();
    int v = s[t];
    __syncthreads();
    #pragma unroll
    for (int off = 1; off < 512; off <<= 1) {
        int tv = (t >= off) ? s[t - off] : 0;
        __syncthreads();
        s[t] += tv;
        __syncthreads();
    }
    lbase[t] = s[t] - v;
    cur[t] = 0;
    gwin[t] = (t < NB) ? (cmat[(size_t)t * NCHUNK + c] + bbase[t]) : 0;
    __syncthreads();
    // pass B: scatter record into chunk-bucket-sorted LDS order
    for (int i = t; i < nv; i += 512) {
        int4   sv = s4[i];
        int4   dv = d4[i];
        float4 wv = w4[i];
        int b, r;
        b = dv.x >> BSH; r = atomicAdd(&cur[b], 1);
        lrec[lbase[b] + r] = make_int2(sv.x | ((dv.x & (BSZ-1)) << 24), __float_as_int(wv.x));
        b = dv.y >> BSH; r = atomicAdd(&cur[b], 1);
        lrec[lbase[b] + r] = make_int2(sv.y | ((dv.y & (BSZ-1)) << 24), __float_as_int(wv.y));
        b = dv.z >> BSH; r = atomicAdd(&cur[b], 1);
        lrec[lbase[b] + r] = make_int2(sv.z | ((dv.z & (BSZ-1)) << 24), __float_as_int(wv.z));
        b = dv.w >> BSH; r = atomicAdd(&cur[b], 1);
        lrec[lbase[b] + r] = make_int2(sv.w | ((dv.w & (BSZ-1)) << 24), __float_as_int(wv.w));
    }
    for (int e = e0 + (nv << 2) + t; e < e1; e += 512) {
        int d = dst[e];
        int b = d >> BSH;
        int r = atomicAdd(&cur[b], 1);
        lrec[lbase[b] + r] = make_int2(src[e] | ((d & (BSZ-1)) << 24), __float_as_int(ew[e]));
    }
    __syncthreads();
    // pass C: per-bucket LDS -> global copy (contiguous within bucket => coalesced)
    int hw = t >> 5, sl = t & 31;            // 16 half-waves x 32 lanes
    for (int b = hw; b < NB; b += 16) {
        int lb = lbase[b], cn = cur[b], gw = gwin[b];
        for (int i = sl; i < cn; i += 32) recs[gw + i] = lrec[lb + i];
    }
}

// ---------- per-bucket counting sort via inverse permutation + FUSED layer-1 GEMM ----------
// sort phase: extern LDS holds inv16 (24 KB); gemm phase REUSES it for xs (35 KB) +
// W1s (8.75 KB). dsum (block's 256 nodes) is still live in LDS => dinv free.
// 44.8 KB extern + 3 KB statics -> 3 blocks/CU: all 391 blocks co-resident.
__global__ __launch_bounds__(512) void k_sort(
        const int* __restrict__ boff, const int2* __restrict__ recs_in,
        int2* __restrict__ recs_out, int* __restrict__ row_ptr,
        float* __restrict__ dinv, const float* __restrict__ x,
        const float* __restrict__ W1, __half* __restrict__ g1, int n) {
    extern __shared__ char smem[];
    unsigned short* inv16 = (unsigned short*)smem;   // SCAP entries (24 KB), sort phase
    float* xs  = (float*)smem;                       // 256*35 floats (35840 B), gemm phase
    float* W1s = (float*)(smem + (size_t)BSZ * FIN * 4);  // 35*64 floats (8960 B)
    __shared__ int   hcnt[BSZ];
    __shared__ int   hoff[BSZ];
    __shared__ float dsum[BSZ];
    int b = blockIdx.x, t = threadIdx.x;
    if (t < BSZ) { hcnt[t] = 0; dsum[t] = 1.0f; }   // self-loop weight
    __syncthreads();
    int s0 = boff[b], s1 = boff[b + 1];
    int cnt = s1 - s0;
    // pass 1: histogram + weighted degree (coalesced global read)
    for (int i = t; i < cnt; i += 512) {
        int2 rc = recs_in[s0 + i];
        int dl = ((unsigned)rc.x) >> 24;
        atomicAdd(&hcnt[dl], 1);
        atomicAdd(&dsum[dl], __int_as_float(rc.y));
    }
    __syncthreads();
    int v = 0;
    if (t < BSZ) { v = hcnt[t]; hoff[t] = v; }
    __syncthreads();
    #pragma unroll
    for (int off = 1; off < BSZ; off <<= 1) {
        int tv = 0;
        if (t < BSZ && t >= off) tv = hoff[t - off];
        __syncthreads();
        if (t < BSZ) hoff[t] += tv;
        __syncthreads();
    }
    if (t < BSZ) {
        int excl = hoff[t] - v;
        int node = b * BSZ + t;
        if (node < n) {
            row_ptr[node] = s0 + excl;
            dinv[node] = rsqrtf(dsum[t]);
            if (node == n - 1) row_ptr[n] = s1;
        }
        hcnt[t] = excl;           // reuse as local cursor
    }
    __syncthreads();
    if (cnt <= SCAP) {
        // pass 2: positions -> inverse index (cnt <= SCAP < 65536 fits u16)
        for (int i = t; i < cnt; i += 512) {
            int2 rc = recs_in[s0 + i];
            int dl = ((unsigned)rc.x) >> 24;
            int pos = atomicAdd(&hcnt[dl], 1);
            inv16[pos] = (unsigned short)i;
        }
        __syncthreads();
        // pass 3: linear positions -> coalesced stores
        for (int o = t; o < cnt; o += 512) {
            int2 rc = recs_in[s0 + inv16[o]];
            recs_out[s0 + o] = make_int2((rc.x & 0xFFFFFF) << GSH, rc.y);
        }
    } else {
        // fallback (bucket larger than SCAP — not expected): direct scatter
        for (int i = t; i < cnt; i += 512) {
            int2 rc = recs_in[s0 + i];
            int dl = ((unsigned)rc.x) >> 24;
            int pos = atomicAdd(&hcnt[dl], 1);
            recs_out[s0 + pos] = make_int2((rc.x & 0xFFFFFF) << GSH, rc.y);
        }
    }
    __syncthreads();
    // ---- fused layer-1 GEMM for this block's nodes: g1 = fp16(dinv * x @ W1) ----
    int row0 = b * BSZ;
    int nrows = min(BSZ, n - row0);
    if (nrows <= 0) return;
    for (int i = t; i < (FIN * F1) / 4; i += 512) ((float4*)W1s)[i] = ((const float4*)W1)[i];
    const float* xbase = x + (size_t)row0 * FIN;   // byte off row0*140 (16B-aligned)
    int tot = nrows * FIN;
    int totv = tot >> 2;
    for (int i = t; i < totv; i += 512) ((float4*)xs)[i] = ((const float4*)xbase)[i];
    for (int i = (totv << 2) + t; i < tot; i += 512) xs[i] = xbase[i];
    __syncthreads();
    int f = t & 63, w8 = t >> 6;                   // 8 waves x 64 features
    for (int nl = w8; nl < nrows; nl += 8) {
        float acc = 0.0f;
        #pragma unroll
        for (int k = 0; k < FIN; k++) acc += xs[nl * FIN + k] * W1s[k * F1 + f];
        g1[(size_t)(row0 + nl) * F1 + f] = __float2half(acc * rsqrtf(dsum[nl]));
    }
}

// ---------- fused: layer-1 gather (fp16 rows, 16-way MLP, prescaled offsets)
// ---------- + ReLU + layer-2 GEMM (64->2) ----------
__global__ void k_gather1(const int* __restrict__ rp, const int2* __restrict__ csr,
                          const __half* __restrict__ g1,
                          const float* __restrict__ dinv, const float* __restrict__ b1,
                          const float* __restrict__ W2, float* __restrict__ g2, int n) {
    int wid = (int)((blockIdx.x * (long long)blockDim.x + threadIdx.x) >> 6);
    int f = threadIdx.x & 63;
    if (wid >= n) return;
    const char* g1b = (const char*)g1 + f * 2;   // lane's feature column
    int start = rp[wid], end = rp[wid + 1];
    float acc = 0.0f;
    int e = start;
    for (; e + 16 <= end; e += 16) {           // 16 row-gathers in flight
        float a[16];
        int2 r[16];
        #pragma unroll
        for (int j = 0; j < 16; j++) r[j] = csr[e + j];
        #pragma unroll
        for (int j = 0; j < 16; j++)
            a[j] = __half2float(*(const __half*)(g1b + (unsigned)r[j].x));
        #pragma unroll
        for (int j = 0; j < 16; j++) acc += __int_as_float(r[j].y) * a[j];
    }
    for (; e + 4 <= end; e += 4) {
        int2 r0 = csr[e], r1 = csr[e+1], r2 = csr[e+2], r3 = csr[e+3];
        float a0 = __half2float(*(const __half*)(g1b + (unsigned)r0.x));
        float a1 = __half2float(*(const __half*)(g1b + (unsigned)r1.x));
        float a2 = __half2float(*(const __half*)(g1b + (unsigned)r2.x));
        float a3 = __half2float(*(const __half*)(g1b + (unsigned)r3.x));
        acc += __int_as_float(r0.y) * a0; acc += __int_as_float(r1.y) * a1;
        acc += __int_as_float(r2.y) * a2; acc += __int_as_float(r3.y) * a3;
    }
    for (; e < end; e++) {
        int2 r = csr[e];
        acc += __int_as_float(r.y) * __half2float(*(const __half*)(g1b + (unsigned)r.x));
    }
    float dv = dinv[wid];
    float h = dv * (acc + __half2float(g1[(size_t)wid * F1 + f])) + b1[f]; // self-loop w=1
    h = h > 0.0f ? h : 0.0f;
    float2 w2v = ((const float2*)W2)[f];
    float z0 = h * w2v.x, z1 = h * w2v.y;
    #pragma unroll
    for (int off = 32; off > 0; off >>= 1) {
        z0 += __shfl_xor(z0, off, 64);
        z1 += __shfl_xor(z1, off, 64);
    }
    if (f == 0) {
        g2[(size_t)wid * 2 + 0] = dv * z0;
        g2[(size_t)wid * 2 + 1] = dv * z1;
    }
}

// ---------- fused: layer-2 gather (2 nodes/wave, 32 lanes each) + bias + log_softmax ----------
__global__ void k_gather2(const int* __restrict__ rp, const int2* __restrict__ csr,
                          const float* __restrict__ g2,
                          const float* __restrict__ dinv, const float* __restrict__ b2,
                          float* __restrict__ out, int n) {
    int w = (int)((blockIdx.x * (long long)blockDim.x + threadIdx.x) >> 6);
    int lane = threadIdx.x & 63;
    int half = lane >> 5, sub = lane & 31;
    int node = w * 2 + half;
    if (node >= n) return;                      // uniform within each 32-lane half
    const char* g2b = (const char*)g2;
    int start = rp[node], end = rp[node + 1];
    float a0 = 0.0f, a1 = 0.0f;
    int e = start + sub;
    for (; e + 96 < end; e += 128) {            // 4 gathers in flight, stride 32
        int2 q0 = csr[e], q1 = csr[e + 32], q2 = csr[e + 64], q3 = csr[e + 96];
        float2 v0 = *(const float2*)(g2b + (((unsigned)q0.x) >> 4));
        float2 v1 = *(const float2*)(g2b + (((unsigned)q1.x) >> 4));
        float2 v2 = *(const float2*)(g2b + (((unsigned)q2.x) >> 4));
        float2 v3 = *(const float2*)(g2b + (((unsigned)q3.x) >> 4));
        a0 += __int_as_float(q0.y) * v0.x; a1 += __int_as_float(q0.y) * v0.y;
        a0 += __int_as_float(q1.y) * v1.x; a1 += __int_as_float(q1.y) * v1.y;
        a0 += __int_as_float(q2.y) * v2.x; a1 += __int_as_float(q2.y) * v2.y;
        a0 += __int_as_float(q3.y) * v3.x; a1 += __int_as_float(q3.y) * v3.y;
    }
    for (; e < end; e += 32) {
        int2 r = csr[e];
        float wt = __int_as_float(r.y);
        float2 gv = *(const float2*)(g2b + (((unsigned)r.x) >> 4));
        a0 += wt * gv.x; a1 += wt * gv.y;
    }
    #pragma unroll
    for (int off = 16; off > 0; off >>= 1) {    // reduce within the 32-lane half
        a0 += __shfl_xor(a0, off, 64);
        a1 += __shfl_xor(a1, off, 64);
    }
    if (sub == 0) {
        float dv = dinv[node];
        float2 sv = ((const float2*)g2)[node];       // self-loop
        float z0 = dv * (a0 + sv.x) + b2[0];
        float z1 = dv * (a1 + sv.y) + b2[1];
        float m = fmaxf(z0, z1);
        float lse = m + logf(expf(z0 - m) + expf(z1 - m));
        ((float2*)out)[node] = make_float2(z0 - lse, z1 - lse);
    }
}

extern "C" void kernel_launch(void* const* d_in, const int* in_sizes, int n_in,
                              void* d_out, int out_size, void* d_ws, size_t ws_size,
                              hipStream_t stream) {
    const float* x  = (const float*)d_in[0];
    const int*   ei = (const int*)d_in[1];    // [2, E]: src row then dst row
    const float* ew = (const float*)d_in[2];
    const float* W1 = (const float*)d_in[3];
    const float* b1 = (const float*)d_in[4];
    const float* W2 = (const float*)d_in[5];
    const float* b2 = (const float*)d_in[6];
    float* out = (float*)d_out;

    int n = in_sizes[0] / FIN;
    int E = in_sizes[2];
    const int* src = ei;
    const int* dst = ei + E;
    int NB = (n + BSZ - 1) / BSZ;             // 391 for n=100000 (<= MAXNB)
    int NCHUNK = (E + PCH - 1) / PCH;         // 391 for E=3.2M (<= 512 for k_scan_row)
    int M = NB * NCHUNK;

    // workspace carve-out, 16B-aligned
    char* ws = (char*)d_ws;
    size_t off = 0;
    auto alloc = [&](size_t bytes) -> void* {
        void* p = ws + off;
        off += (bytes + 15) & ~(size_t)15;
        return p;
    };
    int*    cmat    = (int*)   alloc((size_t)M * 4);      // 612 KB placement matrix
    int*    rsum    = (int*)   alloc((size_t)NB * 4);
    int*    bbase   = (int*)   alloc((size_t)NB * 4);
    int*    boff    = (int*)   alloc((size_t)(NB + 1) * 4);
    int*    row_ptr = (int*)   alloc((size_t)(n + 1) * 4);
    float*  dinv    = (float*) alloc((size_t)n * 4);
    int2*   recs_a  = (int2*)  alloc((size_t)E * 8);      // 25.6 MB (bucket order)
    int2*   recs_b  = (int2*)  alloc((size_t)E * 8);      // 25.6 MB (node order)
    __half* g1      = (__half*)alloc((size_t)n * F1 * 2); // 12.8 MB
    float*  g2      = (float*) alloc((size_t)n * 2 * 4);

    size_t place_lds = (size_t)PCH * 8;                       // lrec = 64 KB
    size_t sort_lds  = (size_t)BSZ * FIN * 4 + (size_t)FIN * F1 * 4;  // 44.8 KB (>= SCAP*2)

    int g2_waves = (n + 1) / 2 + 1;           // 2 nodes per wave

    k_hist     <<<NCHUNK, 256, 0, stream>>>(dst, cmat, E, NB, NCHUNK);
    k_scan_row <<<NB, 512, 0, stream>>>(cmat, rsum, NCHUNK);
    k_scan_buck<<<1, 1024, 0, stream>>>(rsum, bbase, boff, NB, E);
    k_place    <<<NCHUNK, 512, place_lds, stream>>>(src, dst, ew, cmat, bbase, recs_a, E, NB, NCHUNK);
    k_sort     <<<NB, 512, sort_lds, stream>>>(boff, recs_a, recs_b, row_ptr, dinv, x, W1, g1, n);
    k_gather1  <<<(n + 3) / 4, 256, 0, stream>>>(row_ptr, recs_b, g1, dinv, b1, W2, g2, n);
    k_gather2  <<<(g2_waves + 3) / 4, 256, 0, stream>>>(row_ptr, recs_b, g2, dinv, b2, out, n);
}